// Round 5
// baseline (574.183 us; speedup 1.0000x reference)
//
#include <hip/hip_runtime.h>
#include <hip/hip_bf16.h>
#include <stdint.h>

#define BATCH 128
#define SEQ   512
#define NW    6
#define DIM   64
#define NELEM (BATCH * SEQ * NW)   // 393216
#define PI_F  3.14159265358979323846f

// ---------------------------------------------------------------------------
// DPP wave-64 sum (VALU pipe only): row_shr 1/2/4/8 + row_bcast15/31,
// total lands in lane 63, broadcast via readlane.
// ---------------------------------------------------------------------------
#define DPP_ADD(x, ctrl) \
    ((x) + __int_as_float(__builtin_amdgcn_update_dpp( \
        0, __float_as_int(x), (ctrl), 0xF, 0xF, false)))

__device__ __forceinline__ float wave_sum64(float v) {
    v = DPP_ADD(v, 0x111);   // row_shr:1
    v = DPP_ADD(v, 0x112);   // row_shr:2
    v = DPP_ADD(v, 0x114);   // row_shr:4
    v = DPP_ADD(v, 0x118);   // row_shr:8
    v = DPP_ADD(v, 0x142);   // row_bcast:15
    v = DPP_ADD(v, 0x143);   // row_bcast:31
    return __int_as_float(__builtin_amdgcn_readlane(__float_as_int(v), 63));
}

// Branch-free sincos(h/2) for |h| <= 1 (h is a Z-expectation, so guaranteed).
// Taylor in u = h^2; max err ~1e-7 over the domain.
__device__ __forceinline__ void sincos_half(float h, float& s, float& c) {
    const float u = h * h;
    c = fmaf(u, fmaf(u, fmaf(u, -2.1701389e-5f, 2.6041667e-3f), -0.125f), 1.0f);
    s = h * fmaf(u, fmaf(u, fmaf(u, -1.5501e-6f, 2.6041667e-4f), -2.0833333e-2f), 0.5f);
}

// ---------------------------------------------------------------------------
// Kernel 1: bf16-vs-f32 detection on `angles` (U(0,pi) data).
// ---------------------------------------------------------------------------
__global__ void k_detect(const uint32_t* __restrict__ a, int* __restrict__ flag) {
    __shared__ int cnt;
    if (threadIdx.x == 0) cnt = 0;
    __syncthreads();
    uint32_t w = a[threadIdx.x];
    uint32_t e = (w >> 8) & 0xFFu;
    if (e >= 0x3Au && e <= 0x41u) atomicAdd(&cnt, 1);
    __syncthreads();
    if (threadIdx.x == 0) *flag = (cnt >= 128) ? 1 : 0;   // 1 = bf16
}

__device__ __forceinline__ float ldf(const void* p, int i, bool bf) {
    if (bf) {
        uint32_t u = (uint32_t)((const uint16_t*)p)[i];
        return __uint_as_float(u << 16);
    }
    return ((const float*)p)[i];
}

// ---------------------------------------------------------------------------
// Kernel 2: inputs -> f32 ws; precompute cos(x), sin(x) (FULL angle, used by
// the observable-rotation identity). cs layout: [b][t][w][2].
// misc: [0..3]=poly, [4..39]=fwd, [40..75]=bwd, [76]=fc, [77]=bc.
// ---------------------------------------------------------------------------
__global__ void k_convert(const void* ang, const void* poly, const void* fp,
                          const void* bp, const void* fc, const void* bc,
                          float* __restrict__ cs, float* __restrict__ misc,
                          const int* __restrict__ flag) {
    const bool bf = (*flag != 0);
    const int i = blockIdx.x * blockDim.x + threadIdx.x;
    if (i < NELEM) {
        float x = ldf(ang, i, bf);
        float s, c;
        __sincosf(x, &s, &c);
        cs[2 * i]     = c;
        cs[2 * i + 1] = s;
    }
    if (i < 4)                    misc[i]            = ldf(poly, i, bf);
    else if (i >= 64 && i < 100)  misc[4 + (i - 64)] = ldf(fp, i - 64, bf);
    else if (i >= 128 && i < 164) misc[40 + (i - 128)] = ldf(bp, i - 128, bf);
    else if (i == 200)            misc[76] = ldf(fc, 0, bf);
    else if (i == 201)            misc[77] = ldf(bc, 0, bf);
}

// ---------------------------------------------------------------------------
// Kernel 3: precompute M[dir] (the full step unitary minus encode/injection)
// as an explicit 64x64 complex matrix by evolving basis columns.
// Mg layout: [dir][row][col][2] floats. Runs once; perf-irrelevant.
// ---------------------------------------------------------------------------
__global__ void __launch_bounds__(64) k_msetup(const float* __restrict__ misc,
                                               float* __restrict__ Mg) {
    const int p   = threadIdx.x;
    const int col = blockIdx.x & 63;
    const int dir = blockIdx.x >> 6;
    const float* poly = misc;
    const float* prm  = misc + (dir ? 40 : 4);

    float yr = (p == col) ? 1.f : 0.f;
    float yi = 0.f;

#pragma unroll
    for (int d = 0; d < 4; ++d) {
        const float th = 0.5f * PI_F * poly[d] *
                         (float)(6 - 2 * (int)__popc((unsigned)p));
        float s, c;
        __sincosf(th, &s, &c);
        const float nr = yr * c + yi * s;
        const float ni = yi * c - yr * s;
        yr = nr; yi = ni;
#pragma unroll
        for (int k = 0; k < 6; ++k) {
            const int cw = k, tw = (k + 1) % 6;
            const int src = p ^ (((p >> (5 - cw)) & 1) << (5 - tw));
            yr = __shfl(yr, src, 64);
            yi = __shfl(yi, src, 64);
        }
    }

    int idx = 0;
#pragma unroll
    for (int l = 0; l < 2; ++l) {
#pragma unroll
        for (int w = 0; w < 6; ++w) {
            float cx, sx, cy, sy, cz, sz;
            __sincosf(0.5f * prm[idx + 0], &sx, &cx);
            __sincosf(0.5f * prm[idx + 1], &sy, &cy);
            __sincosf(0.5f * prm[idx + 2], &sz, &cz);
            idx += 3;
            const float A = cy * cx, B = sy * sx, C = sy * cx, D = cy * sx;
            const float U00r = cz * A + sz * B, U00i = cz * B - sz * A;
            const float U11r = U00r,            U11i = sz * A - cz * B;
            const float Xr   = cz * C + sz * D, Xi   = sz * C - cz * D;
            const int m  = 1 << (5 - w);
            const int bb = (p >> (5 - w)) & 1;
            const float C1r = bb ? U11r : U00r;
            const float C1i = bb ? U11i : U00i;
            const float C2r = bb ? Xr : -Xr;
            const float C2i = Xi;
            const float pr = __shfl_xor(yr, m, 64);
            const float pi = __shfl_xor(yi, m, 64);
            const float nr = C1r * yr - C1i * yi + C2r * pr - C2i * pi;
            const float ni = C1r * yi + C1i * yr + C2r * pi + C2i * pr;
            yr = nr; yi = ni;
        }
#pragma unroll
        for (int k = 0; k < 5; ++k) {
            const int src = p ^ (((p >> (5 - k)) & 1) << (5 - (k + 1)));
            yr = __shfl(yr, src, 64);
            yi = __shfl(yi, src, 64);
        }
    }

    float* out = Mg + ((size_t)(dir * 64 + p) * 64 + (size_t)col) * 2;
    out[0] = yr;
    out[1] = yi;
}

// ---------------------------------------------------------------------------
// Kernel 4: recurrent sim. One wave per chain; lane p = amplitude p.
// vs r4: (1) encode sincos -> branch-free 8-FMA polynomial (|h|<=1);
// (2) M loaded through a VOLATILE pointer so the 128 floats cannot be
// rematerialized back into the loop — they stay VGPR-resident.
// ---------------------------------------------------------------------------
__global__ void __launch_bounds__(64, 1) k_sim(const float* __restrict__ cs,
                                               const float* __restrict__ Mg,
                                               float* __restrict__ hbuf) {
    const int p     = threadIdx.x;
    const int chain = blockIdx.x;            // 0..255
    const int dir   = chain >> 7;
    const int b     = chain & 127;
    float* orow = hbuf + (size_t)dir * NELEM + (size_t)b * (SEQ * NW);
    const float* csrow = cs + (size_t)b * (SEQ * NW * 2);

    // my row of M: 64 complex (re,im) kept in VGPRs. volatile => loads happen
    // exactly once and cannot be sunk/rematerialized into the loop.
    float2 M[64];
    {
        const volatile float2* mrow =
            (const volatile float2*)(Mg + (size_t)(dir * 64 + p) * 128);
#pragma unroll
        for (int k = 0; k < 64; ++k) {
            M[k].x = mrow[k].x;
            M[k].y = mrow[k].y;
        }
    }

    __shared__ float xs[2][DIM];             // ping-pong x buffer

    int zmask[6];
#pragma unroll
    for (int w = 0; w < 6; ++w) zmask[w] = ((p >> (5 - w)) & 1) << 31;
    bool EB[6];
#pragma unroll
    for (int w = 0; w < 6; ++w) EB[w] = (p >> (5 - w)) & 1;

    float h[6] = {0.f, 0.f, 0.f, 0.f, 0.f, 0.f};

    const int tin0 = dir ? SEQ - 1 : 0;
    const float4* x0p = (const float4*)(csrow + tin0 * 12);
    float4 xq0 = x0p[0], xq1 = x0p[1], xq2 = x0p[2];

    for (int t = 0; t < SEQ; ++t) {
        const int tin  = dir ? (SEQ - 1 - t) : t;
        const int tn   = (t + 1 < SEQ) ? t + 1 : t;
        const int tinn = dir ? (SEQ - 1 - tn) : tn;
        const float4* xnp = (const float4*)(csrow + tinn * 12);
        float4 nx0 = xnp[0], nx1 = xnp[1], nx2 = xnp[2];

        // 1) encode: real product state via polynomial sincos (no branches)
        float amp = 1.f;
#pragma unroll
        for (int w = 0; w < 6; ++w) {
            float s, c;
            sincos_half(h[w], s, c);
            amp *= EB[w] ? s : c;
        }
        float* xb = xs[t & 1];
        xb[p] = amp;
        __syncthreads();

        // 2) matvec y = M x  (x real, uniform-address LDS broadcast reads)
        float2 acc0 = {0.f, 0.f}, acc1 = {0.f, 0.f};
#pragma unroll
        for (int j = 0; j < 16; ++j) {
            const float4 xv = *(const float4*)(xb + 4 * j);
            acc0.x = fmaf(xv.x, M[4 * j].x, acc0.x);
            acc0.y = fmaf(xv.x, M[4 * j].y, acc0.y);
            acc1.x = fmaf(xv.y, M[4 * j + 1].x, acc1.x);
            acc1.y = fmaf(xv.y, M[4 * j + 1].y, acc1.y);
            acc0.x = fmaf(xv.z, M[4 * j + 2].x, acc0.x);
            acc0.y = fmaf(xv.z, M[4 * j + 2].y, acc0.y);
            acc1.x = fmaf(xv.w, M[4 * j + 3].x, acc1.x);
            acc1.y = fmaf(xv.w, M[4 * j + 3].y, acc1.y);
        }
        const float yr = acc0.x + acc1.x;
        const float yi = acc0.y + acc1.y;

        // 3) measurement, injection folded into the observable:
        //    z_w = cos(x_w)<Z_w> - sin(x_w)<X_w>
        const float q = yr * yr + yi * yi;
        float cxw[6], sxw[6];
        cxw[0] = xq0.x; sxw[0] = xq0.y; cxw[1] = xq0.z; sxw[1] = xq0.w;
        cxw[2] = xq1.x; sxw[2] = xq1.y; cxw[3] = xq1.z; sxw[3] = xq1.w;
        cxw[4] = xq2.x; sxw[4] = xq2.y; cxw[5] = xq2.z; sxw[5] = xq2.w;

        float tsum[6];
#pragma unroll
        for (int w = 0; w < 6; ++w) {
            const int m = 1 << (5 - w);
            const float pr = __shfl_xor(yr, m, 64);
            const float pi = __shfl_xor(yi, m, 64);
            const float ac = yr * pr + yi * pi;
            const float sq = __int_as_float(__float_as_int(q) ^ zmask[w]);
            tsum[w] = cxw[w] * sq - sxw[w] * ac;
        }

        // 4) six DPP wave-reductions -> uniform next-h
#pragma unroll
        for (int w = 0; w < 6; ++w) h[w] = wave_sum64(tsum[w]);

        // 5) store z (lanes 0..5)
        float ov = h[0];
#pragma unroll
        for (int w = 1; w < 6; ++w) ov = (p == w) ? h[w] : ov;
        if (p < 6) orow[tin * NW + p] = ov;

        xq0 = nx0; xq1 = nx1; xq2 = nx2;
    }
}

// ---------------------------------------------------------------------------
// Kernel 5: out = sigmoid(fc)*h_fwd + sigmoid(bc)*h_bwd, dtype per flag.
// ---------------------------------------------------------------------------
__global__ void k_combine(const float* __restrict__ hbuf,
                          const float* __restrict__ misc,
                          void* __restrict__ out, const int* __restrict__ flag) {
    const int i = blockIdx.x * blockDim.x + threadIdx.x;
    if (i >= NELEM) return;
    const float sf = 1.f / (1.f + __expf(-misc[76]));
    const float sb = 1.f / (1.f + __expf(-misc[77]));
    const float v = sf * hbuf[i] + sb * hbuf[NELEM + i];
    if (*flag) ((__hip_bfloat16*)out)[i] = __float2bfloat16(v);
    else       ((float*)out)[i] = v;
}

// ---------------------------------------------------------------------------
extern "C" void kernel_launch(void* const* d_in, const int* in_sizes, int n_in,
                              void* d_out, int out_size, void* d_ws, size_t ws_size,
                              hipStream_t stream) {
    const void* ang  = d_in[0];
    const void* poly = d_in[1];
    const void* fp   = d_in[2];
    const void* bp   = d_in[3];
    const void* fc   = d_in[4];
    const void* bc   = d_in[5];

    // ws (floats): cs[2*NELEM] | misc[128] | hbuf[2*NELEM] | M[16384] | flag
    float* cs   = (float*)d_ws;
    float* misc = cs + 2 * NELEM;
    float* hbuf = misc + 128;
    float* Mg   = hbuf + 2 * NELEM;
    int*   flag = (int*)(Mg + 2 * 64 * 64 * 2);

    k_detect<<<1, 256, 0, stream>>>((const uint32_t*)ang, flag);
    k_convert<<<(NELEM + 255) / 256, 256, 0, stream>>>(ang, poly, fp, bp, fc, bc,
                                                       cs, misc, flag);
    k_msetup<<<128, 64, 0, stream>>>(misc, Mg);
    k_sim<<<256, 64, 0, stream>>>(cs, Mg, hbuf);
    k_combine<<<(NELEM + 255) / 256, 256, 0, stream>>>(hbuf, misc, d_out, flag);
}

// Round 6
// 571.870 us; speedup vs baseline: 1.0040x; 1.0040x over previous
//
#include <hip/hip_runtime.h>
#include <hip/hip_bf16.h>
#include <stdint.h>

#define BATCH 128
#define SEQ   512
#define NW    6
#define DIM   64
#define NELEM (BATCH * SEQ * NW)   // 393216
#define PI_F  3.14159265358979323846f

// ---------------------------------------------------------------------------
// DPP wave-64 sum (VALU pipe only): row_shr 1/2/4/8 + row_bcast15/31,
// total lands in lane 63, broadcast via readlane.
// ---------------------------------------------------------------------------
#define DPP_ADD(x, ctrl) \
    ((x) + __int_as_float(__builtin_amdgcn_update_dpp( \
        0, __float_as_int(x), (ctrl), 0xF, 0xF, false)))

__device__ __forceinline__ float wave_sum64(float v) {
    v = DPP_ADD(v, 0x111);   // row_shr:1
    v = DPP_ADD(v, 0x112);   // row_shr:2
    v = DPP_ADD(v, 0x114);   // row_shr:4
    v = DPP_ADD(v, 0x118);   // row_shr:8
    v = DPP_ADD(v, 0x142);   // row_bcast:15
    v = DPP_ADD(v, 0x143);   // row_bcast:31
    return __int_as_float(__builtin_amdgcn_readlane(__float_as_int(v), 63));
}

// Branch-free sincos(h/2) for |h| <= 1 (h = cos*<Z>-sin*<X>, |h|<=1 for a
// pure state). Max err ~1e-7.
__device__ __forceinline__ void sincos_half(float h, float& s, float& c) {
    const float u = h * h;
    c = fmaf(u, fmaf(u, fmaf(u, -2.1701389e-5f, 2.6041667e-3f), -0.125f), 1.0f);
    s = h * fmaf(u, fmaf(u, fmaf(u, -1.5501e-6f, 2.6041667e-4f), -2.0833333e-2f), 0.5f);
}

// ---------------------------------------------------------------------------
// Kernel 1: bf16-vs-f32 detection on `angles` (U(0,pi) data).
// ---------------------------------------------------------------------------
__global__ void k_detect(const uint32_t* __restrict__ a, int* __restrict__ flag) {
    __shared__ int cnt;
    if (threadIdx.x == 0) cnt = 0;
    __syncthreads();
    uint32_t w = a[threadIdx.x];
    uint32_t e = (w >> 8) & 0xFFu;
    if (e >= 0x3Au && e <= 0x41u) atomicAdd(&cnt, 1);
    __syncthreads();
    if (threadIdx.x == 0) *flag = (cnt >= 128) ? 1 : 0;   // 1 = bf16
}

__device__ __forceinline__ float ldf(const void* p, int i, bool bf) {
    if (bf) {
        uint32_t u = (uint32_t)((const uint16_t*)p)[i];
        return __uint_as_float(u << 16);
    }
    return ((const float*)p)[i];
}

// ---------------------------------------------------------------------------
// Kernel 2: inputs -> f32 ws; precompute cos(x), sin(x) (FULL angle, used by
// the observable-rotation identity). cs layout: [b][t][w][2].
// misc: [0..3]=poly, [4..39]=fwd, [40..75]=bwd, [76]=fc, [77]=bc.
// ---------------------------------------------------------------------------
__global__ void k_convert(const void* ang, const void* poly, const void* fp,
                          const void* bp, const void* fc, const void* bc,
                          float* __restrict__ cs, float* __restrict__ misc,
                          const int* __restrict__ flag) {
    const bool bf = (*flag != 0);
    const int i = blockIdx.x * blockDim.x + threadIdx.x;
    if (i < NELEM) {
        float x = ldf(ang, i, bf);
        float s, c;
        __sincosf(x, &s, &c);
        cs[2 * i]     = c;
        cs[2 * i + 1] = s;
    }
    if (i < 4)                    misc[i]            = ldf(poly, i, bf);
    else if (i >= 64 && i < 100)  misc[4 + (i - 64)] = ldf(fp, i - 64, bf);
    else if (i >= 128 && i < 164) misc[40 + (i - 128)] = ldf(bp, i - 128, bf);
    else if (i == 200)            misc[76] = ldf(fc, 0, bf);
    else if (i == 201)            misc[77] = ldf(bc, 0, bf);
}

// ---------------------------------------------------------------------------
// Kernel 3: precompute M[dir] (full step unitary minus encode/injection) as
// an explicit 64x64 complex matrix by evolving basis columns.
// Mg layout: [dir][row][col][2] floats. Runs once; perf-irrelevant.
// ---------------------------------------------------------------------------
__global__ void __launch_bounds__(64) k_msetup(const float* __restrict__ misc,
                                               float* __restrict__ Mg) {
    const int p   = threadIdx.x;
    const int col = blockIdx.x & 63;
    const int dir = blockIdx.x >> 6;
    const float* poly = misc;
    const float* prm  = misc + (dir ? 40 : 4);

    float yr = (p == col) ? 1.f : 0.f;
    float yi = 0.f;

#pragma unroll
    for (int d = 0; d < 4; ++d) {
        const float th = 0.5f * PI_F * poly[d] *
                         (float)(6 - 2 * (int)__popc((unsigned)p));
        float s, c;
        __sincosf(th, &s, &c);
        const float nr = yr * c + yi * s;
        const float ni = yi * c - yr * s;
        yr = nr; yi = ni;
#pragma unroll
        for (int k = 0; k < 6; ++k) {
            const int cw = k, tw = (k + 1) % 6;
            const int src = p ^ (((p >> (5 - cw)) & 1) << (5 - tw));
            yr = __shfl(yr, src, 64);
            yi = __shfl(yi, src, 64);
        }
    }

    int idx = 0;
#pragma unroll
    for (int l = 0; l < 2; ++l) {
#pragma unroll
        for (int w = 0; w < 6; ++w) {
            float cx, sx, cy, sy, cz, sz;
            __sincosf(0.5f * prm[idx + 0], &sx, &cx);
            __sincosf(0.5f * prm[idx + 1], &sy, &cy);
            __sincosf(0.5f * prm[idx + 2], &sz, &cz);
            idx += 3;
            const float A = cy * cx, B = sy * sx, C = sy * cx, D = cy * sx;
            const float U00r = cz * A + sz * B, U00i = cz * B - sz * A;
            const float U11r = U00r,            U11i = sz * A - cz * B;
            const float Xr   = cz * C + sz * D, Xi   = sz * C - cz * D;
            const int m  = 1 << (5 - w);
            const int bb = (p >> (5 - w)) & 1;
            const float C1r = bb ? U11r : U00r;
            const float C1i = bb ? U11i : U00i;
            const float C2r = bb ? Xr : -Xr;
            const float C2i = Xi;
            const float pr = __shfl_xor(yr, m, 64);
            const float pi = __shfl_xor(yi, m, 64);
            const float nr = C1r * yr - C1i * yi + C2r * pr - C2i * pi;
            const float ni = C1r * yi + C1i * yr + C2r * pi + C2i * pr;
            yr = nr; yi = ni;
        }
#pragma unroll
        for (int k = 0; k < 5; ++k) {
            const int src = p ^ (((p >> (5 - k)) & 1) << (5 - (k + 1)));
            yr = __shfl(yr, src, 64);
            yi = __shfl(yi, src, 64);
        }
    }

    float* out = Mg + ((size_t)(dir * 64 + p) * 64 + (size_t)col) * 2;
    out[0] = yr;
    out[1] = yi;
}

// ---------------------------------------------------------------------------
// Kernel 4: recurrent sim. ONE BLOCK (4 waves, 256 thr) per chain.
// Wave k owns M columns [16k,16k+16): 16 complex = 32 VGPRs per lane —
// trivially register-resident (the r4/r5 spill problem is structural here).
// Per step:
//   A (wave0): encode h -> xs[64] in LDS;          barrier
//   B (all):   y_partial[lane] += M_chunk * x_chunk (32 reg FMAs); to LDS;
//              barrier
//   C (wave0): sum 4 partials, measurement (12 bpermute + 6 DPP reductions),
//              h update, store. Waves 1-3 wait at next barrier.
// ---------------------------------------------------------------------------
__global__ void __launch_bounds__(256, 1) k_sim(const float* __restrict__ cs,
                                                const float* __restrict__ Mg,
                                                float* __restrict__ hbuf) {
    const int tid   = threadIdx.x;
    const int lane  = tid & 63;
    const int wv    = tid >> 6;              // wave 0..3
    const int chain = blockIdx.x;            // 0..255
    const int dir   = chain >> 7;
    const int b     = chain & 127;
    float* orow = hbuf + (size_t)dir * NELEM + (size_t)b * (SEQ * NW);
    const float* csrow = cs + (size_t)b * (SEQ * NW * 2);

    // my M chunk: rows = lane, cols = [16*wv, 16*wv+16)
    float2 Mc[16];
    {
        const float2* mrow =
            (const float2*)(Mg + ((size_t)(dir * 64 + lane) * 64 + wv * 16) * 2);
#pragma unroll
        for (int k = 0; k < 16; ++k) Mc[k] = mrow[k];
    }

    __shared__ float  xs[DIM];               // product-state amplitudes
    __shared__ float2 pY[4][DIM];            // per-wave matvec partials

    int zmask[6];
#pragma unroll
    for (int w = 0; w < 6; ++w) zmask[w] = ((lane >> (5 - w)) & 1) << 31;
    bool EB[6];
#pragma unroll
    for (int w = 0; w < 6; ++w) EB[w] = (lane >> (5 - w)) & 1;

    float h[6] = {0.f, 0.f, 0.f, 0.f, 0.f, 0.f};

    const int tin0 = dir ? SEQ - 1 : 0;
    const float4* x0p = (const float4*)(csrow + tin0 * 12);
    float4 xq0 = x0p[0], xq1 = x0p[1], xq2 = x0p[2];

    for (int t = 0; t < SEQ; ++t) {
        // ---- phase A (wave0): encode ----
        if (wv == 0) {
            float amp = 1.f;
#pragma unroll
            for (int w = 0; w < 6; ++w) {
                float s, c;
                sincos_half(h[w], s, c);
                amp *= EB[w] ? s : c;
            }
            xs[lane] = amp;
        }
        __syncthreads();

        // ---- phase B (all waves): matvec chunk, 32 resident-reg FMAs ----
        {
            const float4* xc = (const float4*)(xs + wv * 16);  // wave-uniform
            const float4 x0 = xc[0], x1 = xc[1], x2 = xc[2], x3 = xc[3];
            float xv[16];
            xv[0] = x0.x; xv[1] = x0.y; xv[2]  = x0.z; xv[3]  = x0.w;
            xv[4] = x1.x; xv[5] = x1.y; xv[6]  = x1.z; xv[7]  = x1.w;
            xv[8] = x2.x; xv[9] = x2.y; xv[10] = x2.z; xv[11] = x2.w;
            xv[12] = x3.x; xv[13] = x3.y; xv[14] = x3.z; xv[15] = x3.w;
            float2 acc = {0.f, 0.f};
#pragma unroll
            for (int j = 0; j < 16; ++j) {
                acc.x = fmaf(xv[j], Mc[j].x, acc.x);
                acc.y = fmaf(xv[j], Mc[j].y, acc.y);
            }
            pY[wv][lane] = acc;
        }
        __syncthreads();

        // ---- phase C (wave0): reduce + measure + recur ----
        if (wv == 0) {
            const int tin  = dir ? (SEQ - 1 - t) : t;
            const int tn   = (t + 1 < SEQ) ? t + 1 : t;
            const int tinn = dir ? (SEQ - 1 - tn) : tn;
            const float4* xnp = (const float4*)(csrow + tinn * 12);
            float4 nx0 = xnp[0], nx1 = xnp[1], nx2 = xnp[2];

            const float2 y0 = pY[0][lane], y1 = pY[1][lane];
            const float2 y2 = pY[2][lane], y3 = pY[3][lane];
            const float yr = (y0.x + y1.x) + (y2.x + y3.x);
            const float yi = (y0.y + y1.y) + (y2.y + y3.y);

            // z_w = cos(x_w)<Z_w> - sin(x_w)<X_w>
            const float q = yr * yr + yi * yi;
            float cxw[6], sxw[6];
            cxw[0] = xq0.x; sxw[0] = xq0.y; cxw[1] = xq0.z; sxw[1] = xq0.w;
            cxw[2] = xq1.x; sxw[2] = xq1.y; cxw[3] = xq1.z; sxw[3] = xq1.w;
            cxw[4] = xq2.x; sxw[4] = xq2.y; cxw[5] = xq2.z; sxw[5] = xq2.w;

            float tsum[6];
#pragma unroll
            for (int w = 0; w < 6; ++w) {
                const int m = 1 << (5 - w);
                const float pr = __shfl_xor(yr, m, 64);
                const float pi = __shfl_xor(yi, m, 64);
                const float ac = yr * pr + yi * pi;
                const float sq = __int_as_float(__float_as_int(q) ^ zmask[w]);
                tsum[w] = cxw[w] * sq - sxw[w] * ac;
            }
#pragma unroll
            for (int w = 0; w < 6; ++w) h[w] = wave_sum64(tsum[w]);

            float ov = h[0];
#pragma unroll
            for (int w = 1; w < 6; ++w) ov = (lane == w) ? h[w] : ov;
            if (lane < 6) orow[tin * NW + lane] = ov;

            xq0 = nx0; xq1 = nx1; xq2 = nx2;
        }
    }
}

// ---------------------------------------------------------------------------
// Kernel 5: out = sigmoid(fc)*h_fwd + sigmoid(bc)*h_bwd, dtype per flag.
// ---------------------------------------------------------------------------
__global__ void k_combine(const float* __restrict__ hbuf,
                          const float* __restrict__ misc,
                          void* __restrict__ out, const int* __restrict__ flag) {
    const int i = blockIdx.x * blockDim.x + threadIdx.x;
    if (i >= NELEM) return;
    const float sf = 1.f / (1.f + __expf(-misc[76]));
    const float sb = 1.f / (1.f + __expf(-misc[77]));
    const float v = sf * hbuf[i] + sb * hbuf[NELEM + i];
    if (*flag) ((__hip_bfloat16*)out)[i] = __float2bfloat16(v);
    else       ((float*)out)[i] = v;
}

// ---------------------------------------------------------------------------
extern "C" void kernel_launch(void* const* d_in, const int* in_sizes, int n_in,
                              void* d_out, int out_size, void* d_ws, size_t ws_size,
                              hipStream_t stream) {
    const void* ang  = d_in[0];
    const void* poly = d_in[1];
    const void* fp   = d_in[2];
    const void* bp   = d_in[3];
    const void* fc   = d_in[4];
    const void* bc   = d_in[5];

    // ws (floats): cs[2*NELEM] | misc[128] | hbuf[2*NELEM] | M[16384] | flag
    float* cs   = (float*)d_ws;
    float* misc = cs + 2 * NELEM;
    float* hbuf = misc + 128;
    float* Mg   = hbuf + 2 * NELEM;
    int*   flag = (int*)(Mg + 2 * 64 * 64 * 2);

    k_detect<<<1, 256, 0, stream>>>((const uint32_t*)ang, flag);
    k_convert<<<(NELEM + 255) / 256, 256, 0, stream>>>(ang, poly, fp, bp, fc, bc,
                                                       cs, misc, flag);
    k_msetup<<<128, 64, 0, stream>>>(misc, Mg);
    k_sim<<<256, 256, 0, stream>>>(cs, Mg, hbuf);
    k_combine<<<(NELEM + 255) / 256, 256, 0, stream>>>(hbuf, misc, d_out, flag);
}

// Round 7
// 415.921 us; speedup vs baseline: 1.3805x; 1.3750x over previous
//
#include <hip/hip_runtime.h>
#include <hip/hip_bf16.h>
#include <stdint.h>

#define BATCH 128
#define SEQ   512
#define NW    6
#define DIM   64
#define NELEM (BATCH * SEQ * NW)   // 393216
#define PI_F  3.14159265358979323846f

// ---------------------------------------------------------------------------
// Interleaved 6-way DPP wave-64 reduction: all six dependent chains advance
// stage-by-stage so their latencies overlap. Totals land in lane 63.
// ---------------------------------------------------------------------------
template <int CTRL>
__device__ __forceinline__ void red_stage6(float v[6]) {
#pragma unroll
    for (int w = 0; w < 6; ++w)
        v[w] += __int_as_float(__builtin_amdgcn_update_dpp(
            0, __float_as_int(v[w]), CTRL, 0xF, 0xF, false));
}

// Branch-free sincos(h/2) for |h| <= 1 (h is a Z/X expectation of a pure
// state, so |h| <= 1 guaranteed). Max err ~1e-7.
__device__ __forceinline__ void sincos_half(float h, float& s, float& c) {
    const float u = h * h;
    c = fmaf(u, fmaf(u, fmaf(u, -2.1701389e-5f, 2.6041667e-3f), -0.125f), 1.0f);
    s = h * fmaf(u, fmaf(u, fmaf(u, -1.5501e-6f, 2.6041667e-4f), -2.0833333e-2f), 0.5f);
}

// ---------------------------------------------------------------------------
// Kernel 1: bf16-vs-f32 detection on `angles` (U(0,pi) data).
// ---------------------------------------------------------------------------
__global__ void k_detect(const uint32_t* __restrict__ a, int* __restrict__ flag) {
    __shared__ int cnt;
    if (threadIdx.x == 0) cnt = 0;
    __syncthreads();
    uint32_t w = a[threadIdx.x];
    uint32_t e = (w >> 8) & 0xFFu;
    if (e >= 0x3Au && e <= 0x41u) atomicAdd(&cnt, 1);
    __syncthreads();
    if (threadIdx.x == 0) *flag = (cnt >= 128) ? 1 : 0;   // 1 = bf16
}

__device__ __forceinline__ float ldf(const void* p, int i, bool bf) {
    if (bf) {
        uint32_t u = (uint32_t)((const uint16_t*)p)[i];
        return __uint_as_float(u << 16);
    }
    return ((const float*)p)[i];
}

// ---------------------------------------------------------------------------
// Kernel 2: inputs -> f32 ws; precompute cos(x), sin(x) (FULL angle, used by
// the observable-rotation identity). cs layout: [b][t][w][2].
// misc: [0..3]=poly, [4..39]=fwd, [40..75]=bwd, [76]=fc, [77]=bc.
// ---------------------------------------------------------------------------
__global__ void k_convert(const void* ang, const void* poly, const void* fp,
                          const void* bp, const void* fc, const void* bc,
                          float* __restrict__ cs, float* __restrict__ misc,
                          const int* __restrict__ flag) {
    const bool bf = (*flag != 0);
    const int i = blockIdx.x * blockDim.x + threadIdx.x;
    if (i < NELEM) {
        float x = ldf(ang, i, bf);
        float s, c;
        __sincosf(x, &s, &c);
        cs[2 * i]     = c;
        cs[2 * i + 1] = s;
    }
    if (i < 4)                    misc[i]            = ldf(poly, i, bf);
    else if (i >= 64 && i < 100)  misc[4 + (i - 64)] = ldf(fp, i - 64, bf);
    else if (i >= 128 && i < 164) misc[40 + (i - 128)] = ldf(bp, i - 128, bf);
    else if (i == 200)            misc[76] = ldf(fc, 0, bf);
    else if (i == 201)            misc[77] = ldf(bc, 0, bf);
}

// ---------------------------------------------------------------------------
// Kernel 3: precompute M[dir] (full step unitary minus encode/injection) as
// an explicit 64x64 complex matrix by evolving basis columns.
// Mg layout: [dir][row][col][2] floats. Runs once; perf-irrelevant.
// ---------------------------------------------------------------------------
__global__ void __launch_bounds__(64) k_msetup(const float* __restrict__ misc,
                                               float* __restrict__ Mg) {
    const int p   = threadIdx.x;
    const int col = blockIdx.x & 63;
    const int dir = blockIdx.x >> 6;
    const float* poly = misc;
    const float* prm  = misc + (dir ? 40 : 4);

    float yr = (p == col) ? 1.f : 0.f;
    float yi = 0.f;

#pragma unroll
    for (int d = 0; d < 4; ++d) {
        const float th = 0.5f * PI_F * poly[d] *
                         (float)(6 - 2 * (int)__popc((unsigned)p));
        float s, c;
        __sincosf(th, &s, &c);
        const float nr = yr * c + yi * s;
        const float ni = yi * c - yr * s;
        yr = nr; yi = ni;
#pragma unroll
        for (int k = 0; k < 6; ++k) {
            const int cw = k, tw = (k + 1) % 6;
            const int src = p ^ (((p >> (5 - cw)) & 1) << (5 - tw));
            yr = __shfl(yr, src, 64);
            yi = __shfl(yi, src, 64);
        }
    }

    int idx = 0;
#pragma unroll
    for (int l = 0; l < 2; ++l) {
#pragma unroll
        for (int w = 0; w < 6; ++w) {
            float cx, sx, cy, sy, cz, sz;
            __sincosf(0.5f * prm[idx + 0], &sx, &cx);
            __sincosf(0.5f * prm[idx + 1], &sy, &cy);
            __sincosf(0.5f * prm[idx + 2], &sz, &cz);
            idx += 3;
            const float A = cy * cx, B = sy * sx, C = sy * cx, D = cy * sx;
            const float U00r = cz * A + sz * B, U00i = cz * B - sz * A;
            const float U11r = U00r,            U11i = sz * A - cz * B;
            const float Xr   = cz * C + sz * D, Xi   = sz * C - cz * D;
            const int m  = 1 << (5 - w);
            const int bb = (p >> (5 - w)) & 1;
            const float C1r = bb ? U11r : U00r;
            const float C1i = bb ? U11i : U00i;
            const float C2r = bb ? Xr : -Xr;
            const float C2i = Xi;
            const float pr = __shfl_xor(yr, m, 64);
            const float pi = __shfl_xor(yi, m, 64);
            const float nr = C1r * yr - C1i * yi + C2r * pr - C2i * pi;
            const float ni = C1r * yi + C1i * yr + C2r * pi + C2i * pr;
            yr = nr; yi = ni;
        }
#pragma unroll
        for (int k = 0; k < 5; ++k) {
            const int src = p ^ (((p >> (5 - k)) & 1) << (5 - (k + 1)));
            yr = __shfl(yr, src, 64);
            yi = __shfl(yi, src, 64);
        }
    }

    float* out = Mg + ((size_t)(dir * 64 + p) * 64 + (size_t)col) * 2;
    out[0] = yr;
    out[1] = yi;
}

// ---------------------------------------------------------------------------
// Kernel 4: recurrent sim. ONE BLOCK (4 waves) per chain; wave k owns M
// columns [16k,16k+16) (32 resident VGPRs — validated r6).
// vs r6: the inner loop touches NO global memory (cs staged to LDS up front,
// outputs buffered in LDS, bulk-stored at the end) so barriers drain only
// lgkmcnt; the 12 measurement shuffles are batched before use; the 6 DPP
// reduction chains are interleaved stage-by-stage.
// ---------------------------------------------------------------------------
__global__ void __launch_bounds__(256, 1) k_sim(const float* __restrict__ cs,
                                                const float* __restrict__ Mg,
                                                float* __restrict__ hbuf) {
    const int tid   = threadIdx.x;
    const int lane  = tid & 63;
    const int wv    = tid >> 6;              // wave 0..3
    const int chain = blockIdx.x;            // 0..255
    const int dir   = chain >> 7;
    const int b     = chain & 127;
    float* orow = hbuf + (size_t)dir * NELEM + (size_t)b * (SEQ * NW);
    const float* csrow = cs + (size_t)b * (SEQ * NW * 2);

    __shared__ float  cl[SEQ * 12];          // 24 KB staged cos/sin(x)
    __shared__ float  zb[SEQ * 6];           // 12 KB output buffer
    __shared__ float  xs[DIM];               // product-state amplitudes
    __shared__ float2 pY[4][DIM];            // per-wave matvec partials

    // ---- stage this chain's cos/sin rows into LDS (once) ----
    {
        const float4* src = (const float4*)csrow;   // 1536 float4
        float4* dst = (float4*)cl;
#pragma unroll
        for (int k = 0; k < 6; ++k) {
            const int idx = tid + k * 256;
            dst[idx] = src[idx];
        }
    }

    // ---- my M chunk: rows = lane, cols = [16*wv, 16*wv+16) ----
    float2 Mc[16];
    {
        const float2* mrow =
            (const float2*)(Mg + ((size_t)(dir * 64 + lane) * 64 + wv * 16) * 2);
#pragma unroll
        for (int k = 0; k < 16; ++k) Mc[k] = mrow[k];
    }
    __syncthreads();

    int zmask[6];
#pragma unroll
    for (int w = 0; w < 6; ++w) zmask[w] = ((lane >> (5 - w)) & 1) << 31;
    bool EB[6];
#pragma unroll
    for (int w = 0; w < 6; ++w) EB[w] = (lane >> (5 - w)) & 1;

    float h[6] = {0.f, 0.f, 0.f, 0.f, 0.f, 0.f};

    for (int t = 0; t < SEQ; ++t) {
        // ---- phase A (wave0): encode h -> xs ----
        if (wv == 0) {
            float amp = 1.f;
#pragma unroll
            for (int w = 0; w < 6; ++w) {
                float s, c;
                sincos_half(h[w], s, c);
                amp *= EB[w] ? s : c;
            }
            xs[lane] = amp;
        }
        __syncthreads();

        // ---- phase B (all waves): matvec chunk (resident registers) ----
        {
            const float4* xc = (const float4*)(xs + wv * 16);  // wave-uniform
            const float4 x0 = xc[0], x1 = xc[1], x2 = xc[2], x3 = xc[3];
            float xv[16];
            xv[0] = x0.x; xv[1] = x0.y; xv[2]  = x0.z; xv[3]  = x0.w;
            xv[4] = x1.x; xv[5] = x1.y; xv[6]  = x1.z; xv[7]  = x1.w;
            xv[8] = x2.x; xv[9] = x2.y; xv[10] = x2.z; xv[11] = x2.w;
            xv[12] = x3.x; xv[13] = x3.y; xv[14] = x3.z; xv[15] = x3.w;
            float2 acc = {0.f, 0.f};
#pragma unroll
            for (int j = 0; j < 16; ++j) {
                acc.x = fmaf(xv[j], Mc[j].x, acc.x);
                acc.y = fmaf(xv[j], Mc[j].y, acc.y);
            }
            pY[wv][lane] = acc;
        }
        __syncthreads();

        // ---- phase C (wave0): reduce + measure + recur ----
        if (wv == 0) {
            const int tin = dir ? (SEQ - 1 - t) : t;

            // this step's cos/sin(x) — uniform LDS broadcast reads
            const float4* xr4 = (const float4*)(cl + tin * 12);
            const float4 xq0 = xr4[0], xq1 = xr4[1], xq2 = xr4[2];

            const float2 y0 = pY[0][lane], y1 = pY[1][lane];
            const float2 y2 = pY[2][lane], y3 = pY[3][lane];
            const float yr = (y0.x + y1.x) + (y2.x + y3.x);
            const float yi = (y0.y + y1.y) + (y2.y + y3.y);

            // batched partner shuffles (12 independent, one latency window)
            float pr[6], pi[6];
#pragma unroll
            for (int w = 0; w < 6; ++w) pr[w] = __shfl_xor(yr, 1 << (5 - w), 64);
#pragma unroll
            for (int w = 0; w < 6; ++w) pi[w] = __shfl_xor(yi, 1 << (5 - w), 64);

            const float q = yr * yr + yi * yi;
            float cxw[6], sxw[6];
            cxw[0] = xq0.x; sxw[0] = xq0.y; cxw[1] = xq0.z; sxw[1] = xq0.w;
            cxw[2] = xq1.x; sxw[2] = xq1.y; cxw[3] = xq1.z; sxw[3] = xq1.w;
            cxw[4] = xq2.x; sxw[4] = xq2.y; cxw[5] = xq2.z; sxw[5] = xq2.w;

            float v[6];
#pragma unroll
            for (int w = 0; w < 6; ++w) {
                const float ac = yr * pr[w] + yi * pi[w];
                const float sq = __int_as_float(__float_as_int(q) ^ zmask[w]);
                v[w] = cxw[w] * sq - sxw[w] * ac;
            }

            // interleaved 6-way DPP reduction (chains overlap)
            red_stage6<0x111>(v);   // row_shr:1
            red_stage6<0x112>(v);   // row_shr:2
            red_stage6<0x114>(v);   // row_shr:4
            red_stage6<0x118>(v);   // row_shr:8
            red_stage6<0x142>(v);   // row_bcast:15
            red_stage6<0x143>(v);   // row_bcast:31
#pragma unroll
            for (int w = 0; w < 6; ++w)
                h[w] = __int_as_float(
                    __builtin_amdgcn_readlane(__float_as_int(v[w]), 63));

            // buffer outputs in LDS (global store deferred past the loop)
            float ov = h[0];
#pragma unroll
            for (int w = 1; w < 6; ++w) ov = (lane == w) ? h[w] : ov;
            if (lane < 6) zb[tin * NW + lane] = ov;
        }
    }
    __syncthreads();

    // ---- bulk store outputs: 3072 floats = 768 float4, coalesced ----
    {
        const float4* zs4 = (const float4*)zb;
        float4* go = (float4*)orow;
#pragma unroll
        for (int k = 0; k < 3; ++k) {
            const int idx = tid + k * 256;
            go[idx] = zs4[idx];
        }
    }
}

// ---------------------------------------------------------------------------
// Kernel 5: out = sigmoid(fc)*h_fwd + sigmoid(bc)*h_bwd, dtype per flag.
// ---------------------------------------------------------------------------
__global__ void k_combine(const float* __restrict__ hbuf,
                          const float* __restrict__ misc,
                          void* __restrict__ out, const int* __restrict__ flag) {
    const int i = blockIdx.x * blockDim.x + threadIdx.x;
    if (i >= NELEM) return;
    const float sf = 1.f / (1.f + __expf(-misc[76]));
    const float sb = 1.f / (1.f + __expf(-misc[77]));
    const float v = sf * hbuf[i] + sb * hbuf[NELEM + i];
    if (*flag) ((__hip_bfloat16*)out)[i] = __float2bfloat16(v);
    else       ((float*)out)[i] = v;
}

// ---------------------------------------------------------------------------
extern "C" void kernel_launch(void* const* d_in, const int* in_sizes, int n_in,
                              void* d_out, int out_size, void* d_ws, size_t ws_size,
                              hipStream_t stream) {
    const void* ang  = d_in[0];
    const void* poly = d_in[1];
    const void* fp   = d_in[2];
    const void* bp   = d_in[3];
    const void* fc   = d_in[4];
    const void* bc   = d_in[5];

    // ws (floats): cs[2*NELEM] | misc[128] | hbuf[2*NELEM] | M[16384] | flag
    float* cs   = (float*)d_ws;
    float* misc = cs + 2 * NELEM;
    float* hbuf = misc + 128;
    float* Mg   = hbuf + 2 * NELEM;
    int*   flag = (int*)(Mg + 2 * 64 * 64 * 2);

    k_detect<<<1, 256, 0, stream>>>((const uint32_t*)ang, flag);
    k_convert<<<(NELEM + 255) / 256, 256, 0, stream>>>(ang, poly, fp, bp, fc, bc,
                                                       cs, misc, flag);
    k_msetup<<<128, 64, 0, stream>>>(misc, Mg);
    k_sim<<<256, 256, 0, stream>>>(cs, Mg, hbuf);
    k_combine<<<(NELEM + 255) / 256, 256, 0, stream>>>(hbuf, misc, d_out, flag);
}

// Round 8
// 374.421 us; speedup vs baseline: 1.5335x; 1.1108x over previous
//
#include <hip/hip_runtime.h>
#include <hip/hip_bf16.h>
#include <stdint.h>

#define BATCH 128
#define SEQ   512
#define NW    6
#define DIM   64
#define NELEM (BATCH * SEQ * NW)   // 393216
#define PI_F  3.14159265358979323846f

// ---------------------------------------------------------------------------
// Interleaved 6-way DPP wave-64 reduction: six dependent chains advance
// stage-by-stage so their latencies overlap. Totals land in lane 63.
// ---------------------------------------------------------------------------
template <int CTRL>
__device__ __forceinline__ void red_stage6(float v[6]) {
#pragma unroll
    for (int w = 0; w < 6; ++w)
        v[w] += __int_as_float(__builtin_amdgcn_update_dpp(
            0, __float_as_int(v[w]), CTRL, 0xF, 0xF, false));
}

// Branch-free sincos(h/2) for |h| <= 1 (h is a bounded expectation value).
__device__ __forceinline__ void sincos_half(float h, float& s, float& c) {
    const float u = h * h;
    c = fmaf(u, fmaf(u, fmaf(u, -2.1701389e-5f, 2.6041667e-3f), -0.125f), 1.0f);
    s = h * fmaf(u, fmaf(u, fmaf(u, -1.5501e-6f, 2.6041667e-4f), -2.0833333e-2f), 0.5f);
}

// ---------------------------------------------------------------------------
// Kernel 1: bf16-vs-f32 detection on `angles` (U(0,pi) data).
// ---------------------------------------------------------------------------
__global__ void k_detect(const uint32_t* __restrict__ a, int* __restrict__ flag) {
    __shared__ int cnt;
    if (threadIdx.x == 0) cnt = 0;
    __syncthreads();
    uint32_t w = a[threadIdx.x];
    uint32_t e = (w >> 8) & 0xFFu;
    if (e >= 0x3Au && e <= 0x41u) atomicAdd(&cnt, 1);
    __syncthreads();
    if (threadIdx.x == 0) *flag = (cnt >= 128) ? 1 : 0;   // 1 = bf16
}

__device__ __forceinline__ float ldf(const void* p, int i, bool bf) {
    if (bf) {
        uint32_t u = (uint32_t)((const uint16_t*)p)[i];
        return __uint_as_float(u << 16);
    }
    return ((const float*)p)[i];
}

// ---------------------------------------------------------------------------
// Kernel 2: inputs -> f32 ws; precompute cos(x), sin(x) (full angle).
// cs layout: [b][t][w][2]. misc: [0..3]=poly, [4..39]=fwd, [40..75]=bwd,
// [76]=fc, [77]=bc.
// ---------------------------------------------------------------------------
__global__ void k_convert(const void* ang, const void* poly, const void* fp,
                          const void* bp, const void* fc, const void* bc,
                          float* __restrict__ cs, float* __restrict__ misc,
                          const int* __restrict__ flag) {
    const bool bf = (*flag != 0);
    const int i = blockIdx.x * blockDim.x + threadIdx.x;
    if (i < NELEM) {
        float x = ldf(ang, i, bf);
        float s, c;
        __sincosf(x, &s, &c);
        cs[2 * i]     = c;
        cs[2 * i + 1] = s;
    }
    if (i < 4)                    misc[i]            = ldf(poly, i, bf);
    else if (i >= 64 && i < 100)  misc[4 + (i - 64)] = ldf(fp, i - 64, bf);
    else if (i >= 128 && i < 164) misc[40 + (i - 128)] = ldf(bp, i - 128, bf);
    else if (i == 200)            misc[76] = ldf(fc, 0, bf);
    else if (i == 201)            misc[77] = ldf(bc, 0, bf);
}

// ---------------------------------------------------------------------------
// Kernel 3: precompute M[dir] (full step unitary minus encode/injection) as
// an explicit 64x64 complex matrix by evolving basis columns.
// Mg layout: [dir][row][col][2] floats. Runs once; perf-irrelevant.
// ---------------------------------------------------------------------------
__global__ void __launch_bounds__(64) k_msetup(const float* __restrict__ misc,
                                               float* __restrict__ Mg) {
    const int p   = threadIdx.x;
    const int col = blockIdx.x & 63;
    const int dir = blockIdx.x >> 6;
    const float* poly = misc;
    const float* prm  = misc + (dir ? 40 : 4);

    float yr = (p == col) ? 1.f : 0.f;
    float yi = 0.f;

#pragma unroll
    for (int d = 0; d < 4; ++d) {
        const float th = 0.5f * PI_F * poly[d] *
                         (float)(6 - 2 * (int)__popc((unsigned)p));
        float s, c;
        __sincosf(th, &s, &c);
        const float nr = yr * c + yi * s;
        const float ni = yi * c - yr * s;
        yr = nr; yi = ni;
#pragma unroll
        for (int k = 0; k < 6; ++k) {
            const int cw = k, tw = (k + 1) % 6;
            const int src = p ^ (((p >> (5 - cw)) & 1) << (5 - tw));
            yr = __shfl(yr, src, 64);
            yi = __shfl(yi, src, 64);
        }
    }

    int idx = 0;
#pragma unroll
    for (int l = 0; l < 2; ++l) {
#pragma unroll
        for (int w = 0; w < 6; ++w) {
            float cx, sx, cy, sy, cz, sz;
            __sincosf(0.5f * prm[idx + 0], &sx, &cx);
            __sincosf(0.5f * prm[idx + 1], &sy, &cy);
            __sincosf(0.5f * prm[idx + 2], &sz, &cz);
            idx += 3;
            const float A = cy * cx, B = sy * sx, C = sy * cx, D = cy * sx;
            const float U00r = cz * A + sz * B, U00i = cz * B - sz * A;
            const float U11r = U00r,            U11i = sz * A - cz * B;
            const float Xr   = cz * C + sz * D, Xi   = sz * C - cz * D;
            const int m  = 1 << (5 - w);
            const int bb = (p >> (5 - w)) & 1;
            const float C1r = bb ? U11r : U00r;
            const float C1i = bb ? U11i : U00i;
            const float C2r = bb ? Xr : -Xr;
            const float C2i = Xi;
            const float pr = __shfl_xor(yr, m, 64);
            const float pi = __shfl_xor(yi, m, 64);
            const float nr = C1r * yr - C1i * yi + C2r * pr - C2i * pi;
            const float ni = C1r * yi + C1i * yr + C2r * pi + C2i * pr;
            yr = nr; yi = ni;
        }
#pragma unroll
        for (int k = 0; k < 5; ++k) {
            const int src = p ^ (((p >> (5 - k)) & 1) << (5 - (k + 1)));
            yr = __shfl(yr, src, 64);
            yi = __shfl(yi, src, 64);
        }
    }

    float* out = Mg + ((size_t)(dir * 64 + p) * 64 + (size_t)col) * 2;
    out[0] = yr;
    out[1] = yi;
}

// ---------------------------------------------------------------------------
// Kernel 4: recurrent sim. ONE BLOCK (4 waves) per chain; wave k owns M
// columns [16k,16k+16) in registers (validated r6/r7).
// vs r7: ONE barrier per step and NO wave0-only phases. Every wave
// redundantly reduces partials + measures + updates h (idle SIMDs anyway);
// the x-chunk for each wave's matvec is computed IN REGISTERS from the
// tensor-product factorization x_{16wv+j} = A_wv * gh[j>>2] * gl[j&3] —
// the xs LDS round-trip and both extra barriers are gone. pY is ping-ponged
// so read(t)/write(t+1) cannot race across the single barrier.
// ---------------------------------------------------------------------------
__global__ void __launch_bounds__(256, 1) k_sim(const float* __restrict__ cs,
                                                const float* __restrict__ Mg,
                                                float* __restrict__ hbuf) {
    const int tid   = threadIdx.x;
    const int lane  = tid & 63;
    const int wv    = tid >> 6;              // wave 0..3
    const int chain = blockIdx.x;            // 0..255
    const int dir   = chain >> 7;
    const int b     = chain & 127;
    float* orow = hbuf + (size_t)dir * NELEM + (size_t)b * (SEQ * NW);
    const float* csrow = cs + (size_t)b * (SEQ * NW * 2);

    __shared__ float  cl[SEQ * 12];          // 24 KB staged cos/sin(x)
    __shared__ float  zb[SEQ * 6];           // 12 KB output buffer
    __shared__ float2 pY[2][4][DIM];         // ping-pong matvec partials, 4 KB

    // ---- stage this chain's cos/sin rows into LDS (once) ----
    {
        const float4* src = (const float4*)csrow;   // 1536 float4
        float4* dst = (float4*)cl;
#pragma unroll
        for (int k = 0; k < 6; ++k) {
            const int idx = tid + k * 256;
            dst[idx] = src[idx];
        }
    }

    // ---- my M chunk: rows = lane, cols = [16*wv, 16*wv+16) ----
    float2 Mc[16];
    {
        const float2* mrow =
            (const float2*)(Mg + ((size_t)(dir * 64 + lane) * 64 + wv * 16) * 2);
#pragma unroll
        for (int k = 0; k < 16; ++k) Mc[k] = mrow[k];
    }

    int zmask[6];
#pragma unroll
    for (int w = 0; w < 6; ++w) zmask[w] = ((lane >> (5 - w)) & 1) << 31;

    float h[6] = {0.f, 0.f, 0.f, 0.f, 0.f, 0.f};

    // ---- encode h -> my 16 x values (registers) -> matvec -> partial ----
    auto encode_matvec = [&](const float hh[6], float2& acc) {
        float cw[6], sw[6];
#pragma unroll
        for (int w = 0; w < 6; ++w) sincos_half(hh[w], sw[w], cw[w]);
        // column c = 16*wv + j ; c bits (MSB..LSB) = wires 0..5
        const float t0 = ((wv >> 1) & 1) ? sw[0] : cw[0];   // wire 0
        const float t1 = (wv & 1) ? sw[1] : cw[1];          // wire 1
        const float A  = t0 * t1;
        float gh[4], gl[4];
        gh[0] = cw[2] * cw[3]; gh[1] = cw[2] * sw[3];
        gh[2] = sw[2] * cw[3]; gh[3] = sw[2] * sw[3];
        gl[0] = cw[4] * cw[5]; gl[1] = cw[4] * sw[5];
        gl[2] = sw[4] * cw[5]; gl[3] = sw[4] * sw[5];
#pragma unroll
        for (int a = 0; a < 4; ++a) gh[a] *= A;
        float2 a0 = {0.f, 0.f}, a1 = {0.f, 0.f};
#pragma unroll
        for (int j = 0; j < 16; ++j) {
            const float xv = gh[j >> 2] * gl[j & 3];
            if (j & 1) {
                a1.x = fmaf(xv, Mc[j].x, a1.x);
                a1.y = fmaf(xv, Mc[j].y, a1.y);
            } else {
                a0.x = fmaf(xv, Mc[j].x, a0.x);
                a0.y = fmaf(xv, Mc[j].y, a0.y);
            }
        }
        acc.x = a0.x + a1.x;
        acc.y = a0.y + a1.y;
    };

    // staging loads + Mc loads must land before first use
    __syncthreads();

    // ---- peel: step-0 state from h=0 ----
    {
        float2 acc;
        encode_matvec(h, acc);
        pY[0][wv][lane] = acc;
    }
    __syncthreads();

    for (int t = 0; t < SEQ; ++t) {
        const int buf  = t & 1;
        const int tin  = dir ? (SEQ - 1 - t) : t;

        // this step's cos/sin(x) — uniform LDS broadcast (issues early)
        const float4* xr4 = (const float4*)(cl + tin * 12);
        const float4 xq0 = xr4[0], xq1 = xr4[1], xq2 = xr4[2];

        // gather the 4 partials (batched b64 reads, one latency window)
        const float2 y0 = pY[buf][0][lane], y1 = pY[buf][1][lane];
        const float2 y2 = pY[buf][2][lane], y3 = pY[buf][3][lane];
        const float yr = (y0.x + y1.x) + (y2.x + y3.x);
        const float yi = (y0.y + y1.y) + (y2.y + y3.y);

        // batched partner shuffles (12 independent)
        float pr[6], pi[6];
#pragma unroll
        for (int w = 0; w < 6; ++w) pr[w] = __shfl_xor(yr, 1 << (5 - w), 64);
#pragma unroll
        for (int w = 0; w < 6; ++w) pi[w] = __shfl_xor(yi, 1 << (5 - w), 64);

        const float q = yr * yr + yi * yi;
        float cxw[6], sxw[6];
        cxw[0] = xq0.x; sxw[0] = xq0.y; cxw[1] = xq0.z; sxw[1] = xq0.w;
        cxw[2] = xq1.x; sxw[2] = xq1.y; cxw[3] = xq1.z; sxw[3] = xq1.w;
        cxw[4] = xq2.x; sxw[4] = xq2.y; cxw[5] = xq2.z; sxw[5] = xq2.w;

        float v[6];
#pragma unroll
        for (int w = 0; w < 6; ++w) {
            const float ac = yr * pr[w] + yi * pi[w];
            const float sq = __int_as_float(__float_as_int(q) ^ zmask[w]);
            v[w] = cxw[w] * sq - sxw[w] * ac;
        }

        // interleaved 6-way DPP reduction
        red_stage6<0x111>(v);   // row_shr:1
        red_stage6<0x112>(v);   // row_shr:2
        red_stage6<0x114>(v);   // row_shr:4
        red_stage6<0x118>(v);   // row_shr:8
        red_stage6<0x142>(v);   // row_bcast:15
        red_stage6<0x143>(v);   // row_bcast:31
#pragma unroll
        for (int w = 0; w < 6; ++w)
            h[w] = __int_as_float(
                __builtin_amdgcn_readlane(__float_as_int(v[w]), 63));

        // buffer outputs (wave 0 only; read after final barrier)
        if (wv == 0) {
            float ov = h[0];
#pragma unroll
            for (int w = 1; w < 6; ++w) ov = (lane == w) ? h[w] : ov;
            if (lane < 6) zb[tin * NW + lane] = ov;
        }

        // next state's partial into the other buffer
        if (t + 1 < SEQ) {
            float2 acc;
            encode_matvec(h, acc);
            pY[buf ^ 1][wv][lane] = acc;
        }
        __syncthreads();   // the ONLY barrier per step
    }

    // ---- bulk store outputs: 3072 floats = 768 float4, coalesced ----
    {
        const float4* zs4 = (const float4*)zb;
        float4* go = (float4*)orow;
#pragma unroll
        for (int k = 0; k < 3; ++k) {
            const int idx = tid + k * 256;
            go[idx] = zs4[idx];
        }
    }
}

// ---------------------------------------------------------------------------
// Kernel 5: out = sigmoid(fc)*h_fwd + sigmoid(bc)*h_bwd, dtype per flag.
// ---------------------------------------------------------------------------
__global__ void k_combine(const float* __restrict__ hbuf,
                          const float* __restrict__ misc,
                          void* __restrict__ out, const int* __restrict__ flag) {
    const int i = blockIdx.x * blockDim.x + threadIdx.x;
    if (i >= NELEM) return;
    const float sf = 1.f / (1.f + __expf(-misc[76]));
    const float sb = 1.f / (1.f + __expf(-misc[77]));
    const float v = sf * hbuf[i] + sb * hbuf[NELEM + i];
    if (*flag) ((__hip_bfloat16*)out)[i] = __float2bfloat16(v);
    else       ((float*)out)[i] = v;
}

// ---------------------------------------------------------------------------
extern "C" void kernel_launch(void* const* d_in, const int* in_sizes, int n_in,
                              void* d_out, int out_size, void* d_ws, size_t ws_size,
                              hipStream_t stream) {
    const void* ang  = d_in[0];
    const void* poly = d_in[1];
    const void* fp   = d_in[2];
    const void* bp   = d_in[3];
    const void* fc   = d_in[4];
    const void* bc   = d_in[5];

    // ws (floats): cs[2*NELEM] | misc[128] | hbuf[2*NELEM] | M[16384] | flag
    float* cs   = (float*)d_ws;
    float* misc = cs + 2 * NELEM;
    float* hbuf = misc + 128;
    float* Mg   = hbuf + 2 * NELEM;
    int*   flag = (int*)(Mg + 2 * 64 * 64 * 2);

    k_detect<<<1, 256, 0, stream>>>((const uint32_t*)ang, flag);
    k_convert<<<(NELEM + 255) / 256, 256, 0, stream>>>(ang, poly, fp, bp, fc, bc,
                                                       cs, misc, flag);
    k_msetup<<<128, 64, 0, stream>>>(misc, Mg);
    k_sim<<<256, 256, 0, stream>>>(cs, Mg, hbuf);
    k_combine<<<(NELEM + 255) / 256, 256, 0, stream>>>(hbuf, misc, d_out, flag);
}